// Round 5
// baseline (294.792 us; speedup 1.0000x reference)
//
#include <hip/hip_runtime.h>
#include <hip/hip_bf16.h>
#include <math.h>

// Problem constants (fixed by the reference)
#define B_SZ   4096
#define D      64
#define RPB    8192                 // rows per branch = 2*B
#define NCHUNK 8                    // column chunks per gram unit
#define TPC    8                    // 128-col tiles per chunk
#define NPART  16                   // partials per row = NCHUNK * 2 (wn halves)
#define LN2    0.69314718055994531f
#define PRESCALE 2.6857914f         // sqrt(5*log2(e)); X pre-scaled: Gram = base-2 logits
#define GRID   512                  // co-resident: launch_bounds(256,2) => >=2 blocks/CU

typedef __attribute__((ext_vector_type(8))) short  bf16x8;
typedef __attribute__((ext_vector_type(4))) float  f32x4;

__device__ __forceinline__ float fexp2(float x) { return __builtin_amdgcn_exp2f(x); }

// ws layout:
//   Xbf  : 2*8192*64 bf16  = 2 MB   (pre-scaled by PRESCALE)
//   dots : 8192 float      = 32 KB  (v1_i . v2_i, unscaled fp32)
//   P    : 16384*16 float2 = 2 MB   (per-row per-(chunk,wn) (m,s), base-2; user m=0)
//   bar  : 1 unsigned      (grid barrier counter; zeroed by init_kernel)

// ---------------------------------------------------------------------------
// Device-scope grid barrier. All GRID blocks are co-resident (launch bounds).
// Release: threadfence (agent-scope L2 writeback) before arrive;
// Acquire: threadfence (L2 invalidate) after observing all arrivals.
__device__ __forceinline__ void gsync(unsigned* bar, unsigned target) {
    __syncthreads();
    if (threadIdx.x == 0) {
        __threadfence();
        __hip_atomic_fetch_add(bar, 1u, __ATOMIC_RELEASE, __HIP_MEMORY_SCOPE_AGENT);
        while (__hip_atomic_load(bar, __ATOMIC_ACQUIRE, __HIP_MEMORY_SCOPE_AGENT) < target)
            __builtin_amdgcn_s_sleep(2);
        __threadfence();
    }
    __syncthreads();
}

// ---------------------------------------------------------------------------
__global__ void init_kernel(unsigned* bar, float* out) {
    *bar = 0u;
    *out = 0.f;
}

// ---------------------------------------------------------------------------
// One 128-row x 1024-col gram unit with fused per-lane online logsumexp
// (base-2). Identical math to R4's gram_lse_kernel body.
template<int IS_USER>
__device__ void gram_unit(const __hip_bfloat16* __restrict__ Xb,
                          float2* __restrict__ P,
                          __hip_bfloat16 (&Bs)[128][72],
                          int bx, int chunk, int tid)
{
    const int r0   = bx * 128;
    const int wave = tid >> 6, lane = tid & 63;
    const int wm = wave >> 1, wn = wave & 1;
    const int quad = lane >> 4, tx = lane & 15;

    __syncthreads();                    // guard Bs reuse from previous phase/unit
    // Stage A panel through Bs, hoist A fragments to registers (K=64 fits).
    #pragma unroll
    for (int p = 0; p < 4; ++p) {
        int e = p * 256 + tid;
        int row = e >> 3, c8 = e & 7;
        *(uint4*)&Bs[row][c8 * 8] =
            *(const uint4*)(Xb + (size_t)(r0 + row) * D + c8 * 8);
    }
    __syncthreads();
    bf16x8 afr[4][2];
    #pragma unroll
    for (int mt = 0; mt < 4; ++mt)
        #pragma unroll
        for (int ks = 0; ks < 2; ++ks)
            afr[mt][ks] = *(const bf16x8*)&Bs[wm * 64 + mt * 16 + tx][ks * 32 + quad * 8];

    float m_run[16], s_run[16];
    #pragma unroll
    for (int r = 0; r < 16; ++r) { m_run[r] = -INFINITY; s_run[r] = 0.f; }

    const int lrq  = wm * 64 + quad * 4;
    const int lcol = wn * 64 + tx;

    for (int t = 0; t < TPC; ++t) {
        const int ct = chunk * TPC + t;
        const int c0 = ct * 128;
        __syncthreads();                // afr reads (t=0) / prior B-frag reads done
        #pragma unroll
        for (int p = 0; p < 4; ++p) {
            int e = p * 256 + tid;
            int row = e >> 3, c8 = e & 7;
            *(uint4*)&Bs[row][c8 * 8] =
                *(const uint4*)(Xb + (size_t)(c0 + row) * D + c8 * 8);
        }
        __syncthreads();

        f32x4 acc[4][4];
        const f32x4 z = {0.f, 0.f, 0.f, 0.f};
        #pragma unroll
        for (int nt = 0; nt < 4; ++nt) {
            const bf16x8 b0 = *(const bf16x8*)&Bs[wn * 64 + nt * 16 + tx][quad * 8];
            #pragma unroll
            for (int mt = 0; mt < 4; ++mt)
                acc[mt][nt] = __builtin_amdgcn_mfma_f32_16x16x32_bf16(afr[mt][0], b0, z, 0, 0, 0);
        }
        #pragma unroll
        for (int nt = 0; nt < 4; ++nt) {
            const bf16x8 b1 = *(const bf16x8*)&Bs[wn * 64 + nt * 16 + tx][32 + quad * 8];
            #pragma unroll
            for (int mt = 0; mt < 4; ++mt)
                acc[mt][nt] = __builtin_amdgcn_mfma_f32_16x16x32_bf16(afr[mt][1], b1, acc[mt][nt], 0, 0, 0);
        }

        const bool diag = (ct == bx);
        #pragma unroll
        for (int mt = 0; mt < 4; ++mt) {
            #pragma unroll
            for (int rr = 0; rr < 4; ++rr) {
                float y0 = acc[mt][0][rr], y1 = acc[mt][1][rr],
                      y2 = acc[mt][2][rr], y3 = acc[mt][3][rr];
                if (diag) {              // acc already = base-2 logits (pre-scaled X)
                    const int dr = lrq + mt * 16 + rr - lcol;
                    if (dr == 0)  y0 = -INFINITY;
                    if (dr == 16) y1 = -INFINITY;
                    if (dr == 32) y2 = -INFINITY;
                    if (dr == 48) y3 = -INFINITY;
                }
                const int r = mt * 4 + rr;
                if (IS_USER) {
                    s_run[r] += fexp2(y0) + fexp2(y1) + fexp2(y2) + fexp2(y3);
                } else {
                    float mx   = fmaxf(fmaxf(y0, y1), fmaxf(y2, y3));
                    float newm = fmaxf(m_run[r], mx);
                    s_run[r] = s_run[r] * fexp2(m_run[r] - newm)
                             + fexp2(y0 - newm) + fexp2(y1 - newm)
                             + fexp2(y2 - newm) + fexp2(y3 - newm);
                    m_run[r] = newm;
                }
            }
        }
    }

    // Merge across the 16 tx lanes of this wave; (row, chunk, wn) own slot.
    #pragma unroll
    for (int r = 0; r < 16; ++r) {
        float m = IS_USER ? 0.f : m_run[r];
        float s = s_run[r];
        #pragma unroll
        for (int o = 1; o < 16; o <<= 1) {
            if (IS_USER) {
                s += __shfl_xor(s, o, 64);
            } else {
                float om = __shfl_xor(m, o, 64);
                float os = __shfl_xor(s, o, 64);
                float M  = fmaxf(m, om);
                s = s * fexp2(m - M) + os * fexp2(om - M);
                m = M;
            }
        }
        if (tx == 0) {
            const int grow = r0 + wm * 64 + (r >> 2) * 16 + quad * 4 + (r & 3);
            P[(size_t)grow * NPART + chunk * 2 + wn] = make_float2(m, s);
        }
    }
}

// ---------------------------------------------------------------------------
// Fused persistent kernel: gather -> gsync -> user gram unit + item gram unit
// (balanced: every block does one of each) -> gsync -> merge.
__global__ __launch_bounds__(256, 2) void fused_kernel(
    const int* __restrict__ u_idx, const int* __restrict__ i_idx,
    const float* __restrict__ u1e, const float* __restrict__ i1e,
    const float* __restrict__ u2e, const float* __restrict__ i2e,
    __hip_bfloat16* __restrict__ Xbf, float* __restrict__ dots,
    float2* __restrict__ P, unsigned* __restrict__ bar,
    float* __restrict__ out)
{
    __shared__ __align__(16) __hip_bfloat16 Bs[128][72];  // +8 pad, conflict-free
    __shared__ float red[4];

    const int tid  = threadIdx.x;
    const int wave = tid >> 6, lane = tid & 63;

    // ---- Phase 1: gather + normalize + bf16 cast + positive-pair dots ----
    #pragma unroll
    for (int p = 0; p < 4; ++p) {
        const int g      = (blockIdx.x * 4 + wave) * 4 + p;   // 0..8191
        const int branch = g >> 12;
        const int i      = g & (B_SZ - 1);
        const int idx    = (branch == 0) ? u_idx[i] : i_idx[i];
        const float* s1  = (branch == 0) ? u1e : i1e;
        const float* s2  = (branch == 0) ? u2e : i2e;

        float v1 = s1[(size_t)idx * D + lane];
        float v2 = s2[(size_t)idx * D + lane];
        if (branch == 0) {
            float a = v1 * v1, b = v2 * v2;
            #pragma unroll
            for (int o = 32; o > 0; o >>= 1) {
                a += __shfl_xor(a, o, 64);
                b += __shfl_xor(b, o, 64);
            }
            v1 *= rsqrtf(a);
            v2 *= rsqrtf(b);
        }
        float pp = v1 * v2;
        #pragma unroll
        for (int o = 32; o > 0; o >>= 1) pp += __shfl_xor(pp, o, 64);
        if (lane == 0) dots[g] = pp;

        const size_t row1 = (size_t)branch * RPB + i;
        Xbf[row1 * D + lane]          = __float2bfloat16(v1 * PRESCALE);
        Xbf[(row1 + B_SZ) * D + lane] = __float2bfloat16(v2 * PRESCALE);
    }
    gsync(bar, GRID);

    // ---- Phase 2: one user unit + one item unit per block (balanced) ----
    {
        const int bx = blockIdx.x >> 3, chunk = blockIdx.x & 7;
        gram_unit<1>(Xbf, P, Bs, bx, chunk, tid);
        gram_unit<0>(Xbf + (size_t)RPB * D, P + (size_t)RPB * NPART, Bs, bx, chunk, tid);
    }
    gsync(bar, 2 * GRID);

    // ---- Phase 3: merge 16 partials/row -> lse; fold dots; reduce ----
    float vsum = 0.f;
    #pragma unroll
    for (int pass = 0; pass < 2; ++pass) {
        const int row = (blockIdx.x * 2 + pass) * 16 + wave * 4 + (lane >> 4);
        float2 pr = P[(size_t)row * NPART + (lane & 15)];
        float m = pr.x, s = pr.y;
        #pragma unroll
        for (int o = 1; o < 16; o <<= 1) {
            float om = __shfl_xor(m, o, 64);
            float os = __shfl_xor(s, o, 64);
            float M  = fmaxf(m, om);
            s = s * fexp2(m - M) + os * fexp2(om - M);
            m = M;
        }
        if ((lane & 15) == 0) vsum += LN2 * (m + log2f(s));
    }

    float v = vsum * (1.0f / (float)RPB);                 // sum lse_row / (2B)
    if (tid < 16)                                          // positive-pair corr
        v -= dots[blockIdx.x * 16 + tid] * (5.0f / (float)B_SZ);

    #pragma unroll
    for (int o = 32; o > 0; o >>= 1) v += __shfl_xor(v, o, 64);
    if (lane == 0) red[wave] = v;
    __syncthreads();
    if (tid == 0)
        atomicAdd(out, red[0] + red[1] + red[2] + red[3]);
}

// ---------------------------------------------------------------------------
extern "C" void kernel_launch(void* const* d_in, const int* in_sizes, int n_in,
                              void* d_out, int out_size, void* d_ws, size_t ws_size,
                              hipStream_t stream) {
    const int*   u_idx = (const int*)d_in[0];
    const int*   i_idx = (const int*)d_in[1];
    const float* u1e   = (const float*)d_in[2];
    const float* i1e   = (const float*)d_in[3];
    const float* u2e   = (const float*)d_in[4];
    const float* i2e   = (const float*)d_in[5];
    float* out = (float*)d_out;

    __hip_bfloat16* Xbf = (__hip_bfloat16*)d_ws;                    // 2 MB
    float*    dots = (float*)((char*)d_ws + 2 * RPB * D * 2);       // 32 KB
    float2*   P    = (float2*)((char*)dots + RPB * sizeof(float));  // 2 MB
    unsigned* bar  = (unsigned*)((char*)P + (size_t)2 * RPB * NPART * sizeof(float2));

    init_kernel<<<dim3(1), dim3(1), 0, stream>>>(bar, out);
    fused_kernel<<<dim3(GRID), dim3(256), 0, stream>>>(
        u_idx, i_idx, u1e, i1e, u2e, i2e, Xbf, dots, P, bar, out);
}

// Round 6
// 203.942 us; speedup vs baseline: 1.4455x; 1.4455x over previous
//
#include <hip/hip_runtime.h>
#include <hip/hip_bf16.h>
#include <math.h>

// Problem constants (fixed by the reference)
#define B_SZ   4096
#define D      64
#define RPB    8192                 // rows per branch = 2*B
#define NCHUNK 8                    // column chunks (blockIdx.x)
#define TPC    8                    // 128-col tiles per chunk
#define NPART  16                   // partials per row = NCHUNK * 2 (wn halves)
#define LN2    0.69314718055994531f
#define PRESCALE 2.6857914f         // sqrt(5*log2(e)); X pre-scaled: Gram = base-2 logits

typedef __attribute__((ext_vector_type(8))) short  bf16x8;
typedef __attribute__((ext_vector_type(4))) float  f32x4;

__device__ __forceinline__ float fexp2(float x) { return __builtin_amdgcn_exp2f(x); }

// ws layout:
//   Xbf  : 2*8192*64 bf16  = 2 MB   (pre-scaled by PRESCALE)
//   dots : 8192 float      = 32 KB  (v1_i . v2_i, unscaled fp32)
//   P    : 2*8192*16 float2 = 2 MB  (per-row per-(chunk,wn) (m,s), base-2; user m=0)

// ---------------------------------------------------------------------------
__global__ __launch_bounds__(256) void gather_kernel(
    const int* __restrict__ u_idx, const int* __restrict__ i_idx,
    const float* __restrict__ u1e, const float* __restrict__ i1e,
    const float* __restrict__ u2e, const float* __restrict__ i2e,
    __hip_bfloat16* __restrict__ Xbf, float* __restrict__ dots)
{
    const int tid  = threadIdx.x;
    const int wave = tid >> 6, lane = tid & 63;
    const int g      = blockIdx.x * 4 + wave;   // 0..8191
    const int branch = g >> 12;
    const int i      = g & (B_SZ - 1);
    const int idx    = (branch == 0) ? u_idx[i] : i_idx[i];
    const float* s1  = (branch == 0) ? u1e : i1e;
    const float* s2  = (branch == 0) ? u2e : i2e;

    float v1 = s1[(size_t)idx * D + lane];
    float v2 = s2[(size_t)idx * D + lane];
    if (branch == 0) {
        float a = v1 * v1, b = v2 * v2;
        #pragma unroll
        for (int o = 32; o > 0; o >>= 1) {
            a += __shfl_xor(a, o, 64);
            b += __shfl_xor(b, o, 64);
        }
        v1 *= rsqrtf(a);
        v2 *= rsqrtf(b);
    }
    float p = v1 * v2;
    #pragma unroll
    for (int o = 32; o > 0; o >>= 1) p += __shfl_xor(p, o, 64);
    if (lane == 0) dots[g] = p;

    const size_t row1 = (size_t)branch * RPB + i;
    Xbf[row1 * D + lane]          = __float2bfloat16(v1 * PRESCALE);
    Xbf[(row1 + B_SZ) * D + lane] = __float2bfloat16(v2 * PRESCALE);
}

// ---------------------------------------------------------------------------
// One 128-row x 1024-col gram unit + per-lane online logsumexp (base-2).
// IS_USER=1: logits bounded (|y|<=7.3) -> no max tracking, plain exp2-sum.
template<int IS_USER>
__device__ __forceinline__ void gram_body(
    const __hip_bfloat16* __restrict__ Xb, float2* __restrict__ P,
    __hip_bfloat16 (&Bs)[128][72], int bx, int chunk, int tid)
{
    const int r0   = bx * 128;
    const int wave = tid >> 6, lane = tid & 63;
    const int wm = wave >> 1, wn = wave & 1;
    const int quad = lane >> 4, tx = lane & 15;

    // Stage A panel through Bs, hoist A fragments to registers (K=64 fits).
    #pragma unroll
    for (int p = 0; p < 4; ++p) {
        int e = p * 256 + tid;
        int row = e >> 3, c8 = e & 7;
        *(uint4*)&Bs[row][c8 * 8] =
            *(const uint4*)(Xb + (size_t)(r0 + row) * D + c8 * 8);
    }
    __syncthreads();
    bf16x8 afr[4][2];
    #pragma unroll
    for (int mt = 0; mt < 4; ++mt)
        #pragma unroll
        for (int ks = 0; ks < 2; ++ks)
            afr[mt][ks] = *(const bf16x8*)&Bs[wm * 64 + mt * 16 + tx][ks * 32 + quad * 8];

    float m_run[16], s_run[16];
    #pragma unroll
    for (int r = 0; r < 16; ++r) { m_run[r] = -INFINITY; s_run[r] = 0.f; }

    const int lrq  = wm * 64 + quad * 4;
    const int lcol = wn * 64 + tx;

    for (int t = 0; t < TPC; ++t) {
        const int ct = chunk * TPC + t;
        const int c0 = ct * 128;
        __syncthreads();                // afr reads (t=0) / prior B-frag reads done
        #pragma unroll
        for (int p = 0; p < 4; ++p) {
            int e = p * 256 + tid;
            int row = e >> 3, c8 = e & 7;
            *(uint4*)&Bs[row][c8 * 8] =
                *(const uint4*)(Xb + (size_t)(c0 + row) * D + c8 * 8);
        }
        __syncthreads();

        f32x4 acc[4][4];
        const f32x4 z = {0.f, 0.f, 0.f, 0.f};
        #pragma unroll
        for (int nt = 0; nt < 4; ++nt) {
            const bf16x8 b0 = *(const bf16x8*)&Bs[wn * 64 + nt * 16 + tx][quad * 8];
            #pragma unroll
            for (int mt = 0; mt < 4; ++mt)
                acc[mt][nt] = __builtin_amdgcn_mfma_f32_16x16x32_bf16(afr[mt][0], b0, z, 0, 0, 0);
        }
        #pragma unroll
        for (int nt = 0; nt < 4; ++nt) {
            const bf16x8 b1 = *(const bf16x8*)&Bs[wn * 64 + nt * 16 + tx][32 + quad * 8];
            #pragma unroll
            for (int mt = 0; mt < 4; ++mt)
                acc[mt][nt] = __builtin_amdgcn_mfma_f32_16x16x32_bf16(afr[mt][1], b1, acc[mt][nt], 0, 0, 0);
        }

        const bool diag = (ct == bx);
        #pragma unroll
        for (int mt = 0; mt < 4; ++mt) {
            #pragma unroll
            for (int rr = 0; rr < 4; ++rr) {
                float y0 = acc[mt][0][rr], y1 = acc[mt][1][rr],
                      y2 = acc[mt][2][rr], y3 = acc[mt][3][rr];
                if (diag) {              // acc already = base-2 logits (pre-scaled X)
                    const int dr = lrq + mt * 16 + rr - lcol;
                    if (dr == 0)  y0 = -INFINITY;
                    if (dr == 16) y1 = -INFINITY;
                    if (dr == 32) y2 = -INFINITY;
                    if (dr == 48) y3 = -INFINITY;
                }
                const int r = mt * 4 + rr;
                if (IS_USER) {
                    s_run[r] += fexp2(y0) + fexp2(y1) + fexp2(y2) + fexp2(y3);
                } else {
                    float mx   = fmaxf(fmaxf(y0, y1), fmaxf(y2, y3));
                    float newm = fmaxf(m_run[r], mx);
                    s_run[r] = s_run[r] * fexp2(m_run[r] - newm)
                             + fexp2(y0 - newm) + fexp2(y1 - newm)
                             + fexp2(y2 - newm) + fexp2(y3 - newm);
                    m_run[r] = newm;
                }
            }
        }
    }

    // Merge across the 16 tx lanes of this wave; (row, chunk, wn) own slot.
    #pragma unroll
    for (int r = 0; r < 16; ++r) {
        float m = IS_USER ? 0.f : m_run[r];
        float s = s_run[r];
        #pragma unroll
        for (int o = 1; o < 16; o <<= 1) {
            if (IS_USER) {
                s += __shfl_xor(s, o, 64);
            } else {
                float om = __shfl_xor(m, o, 64);
                float os = __shfl_xor(s, o, 64);
                float M  = fmaxf(m, om);
                s = s * fexp2(m - M) + os * fexp2(om - M);
                m = M;
            }
        }
        if (tx == 0) {
            const int grow = r0 + wm * 64 + (r >> 2) * 16 + quad * 4 + (r & 3);
            P[(size_t)grow * NPART + chunk * 2 + wn] = make_float2(m, s);
        }
    }
}

// ---------------------------------------------------------------------------
// Both branches in ONE launch: grid (NCHUNK, 64, 2). 1024 blocks, all
// co-resident (~4 blocks/CU) -> 2x the waves/CU of R4's split launches,
// and user/item blocks mix on the same CUs (load balance).
__global__ __launch_bounds__(256, 4) void gram_lse_kernel(
    const __hip_bfloat16* __restrict__ Xbf, float2* __restrict__ P)
{
    __shared__ __align__(16) __hip_bfloat16 Bs[128][72];  // +8 pad -> ~2-way (free)
    const int chunk = blockIdx.x, bx = blockIdx.y, bz = blockIdx.z;
    if (bz == 0)
        gram_body<1>(Xbf, P, Bs, bx, chunk, threadIdx.x);
    else
        gram_body<0>(Xbf + (size_t)RPB * D, P + (size_t)RPB * NPART,
                     Bs, bx, chunk, threadIdx.x);
}

// ---------------------------------------------------------------------------
// Merge the 16 per-row partials -> lse -> reduce; fold in the positive-pair
// correction from dots[]. grid = 1024 x 256 (each block: 16 rows, 8 dots).
__global__ __launch_bounds__(256) void merge_kernel(
    const float2* __restrict__ P, const float* __restrict__ dots,
    float* __restrict__ out)
{
    __shared__ float red[4];
    const int tid  = threadIdx.x;
    const int wave = tid >> 6, lane = tid & 63;
    const int gw   = blockIdx.x * 4 + wave;        // 0..4095
    const int row  = gw * 4 + (lane >> 4);         // 0..16383
    const int c    = lane & 15;

    float2 p = P[(size_t)row * NPART + c];
    float m = p.x, s = p.y;
    #pragma unroll
    for (int o = 1; o < 16; o <<= 1) {             // online merge across 16 lanes
        float om = __shfl_xor(m, o, 64);
        float os = __shfl_xor(s, o, 64);
        float M  = fmaxf(m, om);
        s = s * fexp2(m - M) + os * fexp2(om - M);
        m = M;
    }

    float v = 0.f;
    if ((lane & 15) == 0)
        v = LN2 * (m + log2f(s)) * (1.0f / (float)RPB);   // lse_row / (2B)
    if (tid < 8)                                           // positive-pair correction
        v -= dots[blockIdx.x * 8 + tid] * (5.0f / (float)B_SZ);

    #pragma unroll
    for (int o = 32; o > 0; o >>= 1) v += __shfl_xor(v, o, 64);
    if (lane == 0) red[wave] = v;
    __syncthreads();
    if (tid == 0)
        atomicAdd(out, red[0] + red[1] + red[2] + red[3]);
}

// ---------------------------------------------------------------------------
extern "C" void kernel_launch(void* const* d_in, const int* in_sizes, int n_in,
                              void* d_out, int out_size, void* d_ws, size_t ws_size,
                              hipStream_t stream) {
    const int*   u_idx = (const int*)d_in[0];
    const int*   i_idx = (const int*)d_in[1];
    const float* u1e   = (const float*)d_in[2];
    const float* i1e   = (const float*)d_in[3];
    const float* u2e   = (const float*)d_in[4];
    const float* i2e   = (const float*)d_in[5];
    float* out = (float*)d_out;

    __hip_bfloat16* Xbf = (__hip_bfloat16*)d_ws;                  // 2 MB
    float*  dots = (float*)((char*)d_ws + 2 * RPB * D * 2);       // 32 KB
    float2* P    = (float2*)((char*)dots + RPB * sizeof(float));  // 2 MB

    hipMemsetAsync(out, 0, sizeof(float), stream);

    gather_kernel<<<dim3(2048), dim3(256), 0, stream>>>(
        u_idx, i_idx, u1e, i1e, u2e, i2e, Xbf, dots);
    gram_lse_kernel<<<dim3(NCHUNK, 64, 2), dim3(256), 0, stream>>>(Xbf, P);
    merge_kernel<<<dim3(1024), dim3(256), 0, stream>>>(P, dots, out);
}